// Round 1
// baseline (792.652 us; speedup 1.0000x reference)
//
#include <hip/hip_runtime.h>

// Sizes
#define NT 1024      // N_TOPICS
#define TD 128       // TOPIC_DIM
#define HID 512      // HIDDEN
#define NH 8         // N_HEADS
#define HD 64        // HEAD_DIM
#define NB 8         // BATCH

// ---------------- time max reduction ----------------
__global__ __launch_bounds__(256) void kmax1(const float* __restrict__ tm, float* __restrict__ part) {
    int idx = blockIdx.x * 256 + threadIdx.x;
    float m = -1e30f;
    for (size_t i = idx; i < (size_t)NB * NT * NT; i += 1024 * 256) m = fmaxf(m, tm[i]);
    __shared__ float red[256];
    red[threadIdx.x] = m; __syncthreads();
    for (int s = 128; s > 0; s >>= 1) {
        if (threadIdx.x < s) red[threadIdx.x] = fmaxf(red[threadIdx.x], red[threadIdx.x + s]);
        __syncthreads();
    }
    if (threadIdx.x == 0) part[blockIdx.x] = red[0];
}

__global__ __launch_bounds__(256) void kmax2(const float* __restrict__ part, float* __restrict__ tmax) {
    float m = -1e30f;
    for (int i = threadIdx.x; i < 1024; i += 256) m = fmaxf(m, part[i]);
    __shared__ float red[256];
    red[threadIdx.x] = m; __syncthreads();
    for (int s = 128; s > 0; s >>= 1) {
        if (threadIdx.x < s) red[threadIdx.x] = fmaxf(red[threadIdx.x], red[threadIdx.x + s]);
        __syncthreads();
    }
    if (threadIdx.x == 0) tmax[0] = red[0];
}

// ---------------- TW' = adj ? exp(0.1*(t - tmax)) : 0 ----------------
__global__ __launch_bounds__(256) void ktw(const float* __restrict__ tm, const int* __restrict__ adj,
                                           const float* __restrict__ tmax, float* __restrict__ TW) {
    size_t idx = ((size_t)blockIdx.x * 256 + threadIdx.x) * 4;
    float tmx = tmax[0];
    float4 t = *(const float4*)(tm + idx);
    int4 a = *(const int4*)(adj + idx);
    float4 r;
    r.x = a.x ? __expf(0.1f * (t.x - tmx)) : 0.f;
    r.y = a.y ? __expf(0.1f * (t.y - tmx)) : 0.f;
    r.z = a.z ? __expf(0.1f * (t.z - tmx)) : 0.f;
    r.w = a.w ? __expf(0.1f * (t.w - tmx)) : 0.f;
    *(float4*)(TW + idx) = r;
}

// ---------------- node0 = emb @ struct_W.T + struct_b  (1024 x 512) ----------------
__global__ __launch_bounds__(256) void knode0(const float* __restrict__ emb, const float* __restrict__ sW,
                                              const float* __restrict__ sb, float* __restrict__ node0) {
    int n = blockIdx.x, t = threadIdx.x;
    __shared__ float er[TD];
    if (t < TD) er[t] = emb[n * TD + t];
    __syncthreads();
    for (int k = t; k < HID; k += 256) {
        const float4* w = (const float4*)(sW + (size_t)k * TD);
        float acc = 0.f;
        #pragma unroll
        for (int i = 0; i < TD / 4; i++) {
            float4 wv = w[i];
            float4 ev = *(const float4*)(er + i * 4);
            acc += wv.x * ev.x + wv.y * ev.y + wv.z * ev.z + wv.w * ev.w;
        }
        node0[(size_t)n * HID + k] = acc + sb[k];
    }
}

// ---------------- GEMM: C[b] (Mx512) = A[b] (Mx512) @ W_layer (512x512) ------------
// W is gat_W for one layer: B[i][h*64+o] = W[h*512*64 + i*64 + o]
// 64x64 tile, 4x4 micro (layer1: small grid fills more CUs)
__global__ __launch_bounds__(256) void kgemm64(const float* __restrict__ A, const float* __restrict__ W,
                                               float* __restrict__ C, size_t strideA, size_t strideC) {
    __shared__ float As[32][68];
    __shared__ float Bs[32][64];
    const float* Ab = A + blockIdx.z * strideA;
    float* Cb = C + blockIdx.z * strideC;
    int t = threadIdx.x;
    int tx = t & 15, ty = t >> 4;
    int m0 = blockIdx.y * 64, n0 = blockIdx.x * 64;
    int head = n0 >> 6;
    float acc[4][4] = {};
    for (int k0 = 0; k0 < HID; k0 += 32) {
        #pragma unroll
        for (int r = 0; r < 8; r++) {
            int mm = (t >> 5) + r * 8, kk = t & 31;
            As[kk][mm] = Ab[(size_t)(m0 + mm) * HID + k0 + kk];
        }
        #pragma unroll
        for (int r = 0; r < 8; r++) {
            int nn = t & 63, kk = (t >> 6) + r * 4;
            Bs[kk][nn] = W[(size_t)head * HID * HD + (size_t)(k0 + kk) * HD + nn];
        }
        __syncthreads();
        #pragma unroll
        for (int kk = 0; kk < 32; kk++) {
            float a[4], b[4];
            #pragma unroll
            for (int x = 0; x < 4; x++) a[x] = As[kk][ty * 4 + x];
            #pragma unroll
            for (int x = 0; x < 4; x++) b[x] = Bs[kk][tx * 4 + x];
            #pragma unroll
            for (int y = 0; y < 4; y++)
                #pragma unroll
                for (int x = 0; x < 4; x++) acc[y][x] = fmaf(a[y], b[x], acc[y][x]);
        }
        __syncthreads();
    }
    #pragma unroll
    for (int y = 0; y < 4; y++) {
        int m = m0 + ty * 4 + y;
        #pragma unroll
        for (int x = 0; x < 4; x++) Cb[(size_t)m * HID + n0 + tx * 4 + x] = acc[y][x];
    }
}

// 128x128 tile, 8x8 micro (layer2: 256 blocks)
__global__ __launch_bounds__(256) void kgemm128(const float* __restrict__ A, const float* __restrict__ W,
                                                float* __restrict__ C, size_t strideA, size_t strideC) {
    __shared__ float As[16][132];
    __shared__ float Bs[16][128];
    const float* Ab = A + blockIdx.z * strideA;
    float* Cb = C + blockIdx.z * strideC;
    int t = threadIdx.x;
    int tx = t & 15, ty = t >> 4;
    int m0 = blockIdx.y * 128, n0 = blockIdx.x * 128;
    float acc[8][8] = {};
    for (int k0 = 0; k0 < HID; k0 += 16) {
        #pragma unroll
        for (int r = 0; r < 8; r++) {
            int mm = (t >> 4) + r * 16, kk = t & 15;
            As[kk][mm] = Ab[(size_t)(m0 + mm) * HID + k0 + kk];
        }
        #pragma unroll
        for (int r = 0; r < 8; r++) {
            int nn = t & 127, kk = (t >> 7) + r * 2;
            int n = n0 + nn;
            Bs[kk][nn] = W[(size_t)(n >> 6) * HID * HD + (size_t)(k0 + kk) * HD + (n & 63)];
        }
        __syncthreads();
        #pragma unroll
        for (int kk = 0; kk < 16; kk++) {
            float a[8], b[8];
            #pragma unroll
            for (int x = 0; x < 8; x++) a[x] = As[kk][ty * 8 + x];
            #pragma unroll
            for (int x = 0; x < 8; x++) b[x] = Bs[kk][tx * 8 + x];
            #pragma unroll
            for (int y = 0; y < 8; y++)
                #pragma unroll
                for (int x = 0; x < 8; x++) acc[y][x] = fmaf(a[y], b[x], acc[y][x]);
        }
        __syncthreads();
    }
    #pragma unroll
    for (int y = 0; y < 8; y++) {
        int m = m0 + ty * 8 + y;
        #pragma unroll
        for (int x = 0; x < 8; x++) Cb[(size_t)m * HID + n0 + tx * 8 + x] = acc[y][x];
    }
}

// ---------------- e_src / e_dst: one wave per (b,h,n) row ----------------
__global__ __launch_bounds__(256) void kedst(const float* __restrict__ H, const float* __restrict__ ga,
                                             float* __restrict__ es, float* __restrict__ ed, int npairs) {
    int wid = threadIdx.x >> 6, lane = threadIdx.x & 63;
    int p = blockIdx.x * 4 + wid;
    if (p >= npairs) return;
    int n = p & (NT - 1);
    int h = (p >> 10) & (NH - 1);
    int b = p >> 13;
    float v = H[((size_t)(b * NT + n)) * HID + h * HD + lane];
    float s = v * ga[h * 2 * HD + lane];
    float d = v * ga[h * 2 * HD + HD + lane];
    for (int m = 32; m > 0; m >>= 1) { s += __shfl_xor(s, m); d += __shfl_xor(d, m); }
    if (lane == 0) { es[p] = s; ed[p] = d; }
}

// ---------------- layer-1 fused attention (all 1024 query rows) ----------------
// lane = query row. acc[o] per lane. H1 / e_dst via wave-uniform (scalar) loads.
#define JC 32
__global__ __launch_bounds__(64) void kattn1(const float* __restrict__ TW, const float* __restrict__ H1,
                                             const float* __restrict__ es, const float* __restrict__ ed,
                                             float* __restrict__ node1) {
    int h = blockIdx.x;      // 8
    int iblk = blockIdx.y;   // 16
    int b = blockIdx.z;      // 8
    int lane = threadIdx.x;  // 64
    int i = iblk * 64 + lane;
    __shared__ float twtile[64][JC + 1];
    float acc[HD];
    #pragma unroll
    for (int o = 0; o < HD; o++) acc[o] = 0.f;
    float l = 0.f;
    float esi = es[h * NT + i];
    const float* twrow = TW + ((size_t)b * NT * NT) + (size_t)iblk * 64 * NT;
    for (int j0 = 0; j0 < NT; j0 += JC) {
        __syncthreads();
        #pragma unroll
        for (int k = 0; k < JC; k++) {  // stage 64 rows x 32 cols, coalesced
            int row = (lane >> 5) + (k << 1);
            int col = lane & 31;
            twtile[row][col] = twrow[(size_t)row * NT + j0 + col];
        }
        __syncthreads();
        float p[JC];
        #pragma unroll
        for (int jj = 0; jj < JC; jj++) {
            float tw = twtile[lane][jj];
            float e = esi + ed[h * NT + j0 + jj];   // uniform -> s_load
            e = fmaxf(e, 0.2f * e);                 // leaky_relu
            e *= tw;
            float pv = (tw == 0.f) ? 0.f : __expf(e);
            l += pv;
            p[jj] = pv;
        }
        #pragma unroll
        for (int jj = 0; jj < JC; jj++) {
            const float* hrow = H1 + (size_t)(j0 + jj) * HID + h * HD;  // uniform -> s_load
            float pj = p[jj];
            #pragma unroll
            for (int o = 0; o < HD; o++) acc[o] = fmaf(pj, hrow[o], acc[o]);
        }
    }
    float invl = 1.f / l;
    float* out = node1 + ((size_t)(b * NT + i)) * HID + h * HD;
    #pragma unroll
    for (int o = 0; o < HD; o++) {
        float v = acc[o] * invl;
        v = v > 0.f ? v : (__expf(v) - 1.f);  // ELU
        out[o] = v;
    }
}

// ---------------- layer-2 attention at the 8 gathered rows only ----------------
__global__ __launch_bounds__(256) void kattn2(const float* __restrict__ TW, const float* __restrict__ H2,
                                              const float* __restrict__ es, const float* __restrict__ ed,
                                              const int* __restrict__ topic_ids, float* __restrict__ feat) {
    int h = blockIdx.x, b = blockIdx.y;
    int t = threadIdx.x;
    __shared__ float pls[NT];
    __shared__ float red[256];
    int qi = topic_ids[b];
    float esq = es[(b * NH + h) * NT + qi];
    const float* twrow = TW + (size_t)b * NT * NT + (size_t)qi * NT;
    float lsum = 0.f;
    for (int j = t; j < NT; j += 256) {
        float tw = twrow[j];
        float e = esq + ed[(b * NH + h) * NT + j];
        e = fmaxf(e, 0.2f * e) * tw;
        float p = (tw == 0.f) ? 0.f : __expf(e);
        pls[j] = p;
        lsum += p;
    }
    red[t] = lsum; __syncthreads();
    for (int s = 128; s > 0; s >>= 1) { if (t < s) red[t] += red[t + s]; __syncthreads(); }
    float invl = 1.f / red[0];
    int o = t & 63, q = t >> 6;
    float acc = 0.f;
    for (int j = q * 256; j < q * 256 + 256; j++)
        acc = fmaf(pls[j], H2[((size_t)(b * NT) + j) * HID + h * HD + o], acc);
    __syncthreads();
    red[t] = acc; __syncthreads();
    if (t < 64) {
        float v = (red[t] + red[t + 64] + red[t + 128] + red[t + 192]) * invl;
        v = v > 0.f ? v : (__expf(v) - 1.f);  // ELU
        feat[b * HID + h * HD + t] = v;
    }
}

// ---------------- final head: combined -> fc1 relu -> fc2 ----------------
__global__ __launch_bounds__(256) void khead(const float* __restrict__ feat, const float* __restrict__ attr,
                                             const float* __restrict__ aW, const float* __restrict__ ab,
                                             const float* __restrict__ fc1W, const float* __restrict__ fc1b,
                                             const float* __restrict__ fc2W, const float* __restrict__ fc2b,
                                             float* __restrict__ out) {
    int b = blockIdx.x, t = threadIdx.x;
    __shared__ float comb[HID];
    __shared__ float red[256];
    float av = attr[b];
    for (int k = t; k < HID; k += 256) comb[k] = feat[b * HID + k] + av * aW[k] + ab[k];
    __syncthreads();
    float part = 0.f;
    for (int k = t; k < HID; k += 256) {
        const float4* wr = (const float4*)(fc1W + (size_t)k * HID);
        float acc = 0.f;
        #pragma unroll 4
        for (int m = 0; m < HID / 4; m++) {
            float4 w4 = wr[m];
            float4 c4 = *(const float4*)(comb + m * 4);
            acc += w4.x * c4.x + w4.y * c4.y + w4.z * c4.z + w4.w * c4.w;
        }
        float hk = fmaxf(acc + fc1b[k], 0.f);
        part = fmaf(hk, fc2W[k], part);
    }
    red[t] = part; __syncthreads();
    for (int s = 128; s > 0; s >>= 1) { if (t < s) red[t] += red[t + s]; __syncthreads(); }
    if (t == 0) out[b] = red[0] + fc2b[0];
}

extern "C" void kernel_launch(void* const* d_in, const int* in_sizes, int n_in,
                              void* d_out, int out_size, void* d_ws, size_t ws_size,
                              hipStream_t stream) {
    const int*   topic_ids = (const int*)d_in[0];
    const int*   adj       = (const int*)d_in[1];
    const float* tm        = (const float*)d_in[2];
    const float* attr      = (const float*)d_in[3];
    const float* emb       = (const float*)d_in[4];
    const float* sW        = (const float*)d_in[5];
    const float* sb        = (const float*)d_in[6];
    const float* aW        = (const float*)d_in[7];
    const float* ab        = (const float*)d_in[8];
    const float* gW        = (const float*)d_in[9];   // (2,8,512,64)
    const float* ga        = (const float*)d_in[10];  // (2,8,128,1)
    const float* fc1W      = (const float*)d_in[11];
    const float* fc1b      = (const float*)d_in[12];
    const float* fc2W      = (const float*)d_in[13];
    const float* fc2b      = (const float*)d_in[14];
    float* out = (float*)d_out;

    float* ws    = (float*)d_ws;
    float* TW    = ws;                      // 8 M
    float* node0 = TW    + (size_t)NB * NT * NT;   // 512 K
    float* H1    = node0 + (size_t)NT * HID;       // 512 K
    float* node1 = H1    + (size_t)NT * HID;       // 4 M
    float* H2    = node1 + (size_t)NB * NT * HID;  // 4 M
    float* es1   = H2    + (size_t)NB * NT * HID;  // 8 K
    float* ed1   = es1 + NH * NT;
    float* es2   = ed1 + NH * NT;                  // 64 K
    float* ed2   = es2 + NB * NH * NT;
    float* feat  = ed2 + NB * NH * NT;             // 4 K
    float* part  = feat + NB * HID;
    float* tmax  = part + 1024;

    kmax1<<<1024, 256, 0, stream>>>(tm, part);
    kmax2<<<1, 256, 0, stream>>>(part, tmax);
    ktw<<<(NB * NT * NT) / 1024, 256, 0, stream>>>(tm, adj, tmax, TW);
    knode0<<<NT, 256, 0, stream>>>(emb, sW, sb, node0);
    // layer 1: h (batch-shared)
    kgemm64<<<dim3(HID / 64, NT / 64, 1), 256, 0, stream>>>(node0, gW, H1, 0, 0);
    kedst<<<(NH * NT) / 4, 256, 0, stream>>>(H1, ga, es1, ed1, NH * NT);
    kattn1<<<dim3(NH, NT / 64, NB), 64, 0, stream>>>(TW, H1, es1, ed1, node1);
    // layer 2: h per batch
    kgemm128<<<dim3(HID / 128, NT / 128, NB), 256, 0, stream>>>(node1, gW + 8 * 512 * 64, H2,
                                                                (size_t)NT * HID, (size_t)NT * HID);
    kedst<<<(NB * NH * NT) / 4, 256, 0, stream>>>(H2, ga + 8 * 128, es2, ed2, NB * NH * NT);
    kattn2<<<dim3(NH, NB), 256, 0, stream>>>(TW, H2, es2, ed2, topic_ids, feat);
    khead<<<NB, 256, 0, stream>>>(feat, attr, aW, ab, fc1W, fc1b, fc2W, fc2b, out);
}

// Round 2
// 510.433 us; speedup vs baseline: 1.5529x; 1.5529x over previous
//
#include <hip/hip_runtime.h>

// Sizes
#define NT 1024      // N_TOPICS
#define TD 128       // TOPIC_DIM
#define HID 512      // HIDDEN
#define NH 8         // N_HEADS
#define HD 64        // HEAD_DIM
#define NB 8         // BATCH

// ---------------- time max reduction ----------------
__global__ __launch_bounds__(256) void kmax1(const float* __restrict__ tm, float* __restrict__ part) {
    int idx = blockIdx.x * 256 + threadIdx.x;
    float m = -1e30f;
    for (size_t i = idx; i < (size_t)NB * NT * NT; i += 1024 * 256) m = fmaxf(m, tm[i]);
    __shared__ float red[256];
    red[threadIdx.x] = m; __syncthreads();
    for (int s = 128; s > 0; s >>= 1) {
        if (threadIdx.x < s) red[threadIdx.x] = fmaxf(red[threadIdx.x], red[threadIdx.x + s]);
        __syncthreads();
    }
    if (threadIdx.x == 0) part[blockIdx.x] = red[0];
}

__global__ __launch_bounds__(256) void kmax2(const float* __restrict__ part, float* __restrict__ tmax) {
    float m = -1e30f;
    for (int i = threadIdx.x; i < 1024; i += 256) m = fmaxf(m, part[i]);
    __shared__ float red[256];
    red[threadIdx.x] = m; __syncthreads();
    for (int s = 128; s > 0; s >>= 1) {
        if (threadIdx.x < s) red[threadIdx.x] = fmaxf(red[threadIdx.x], red[threadIdx.x + s]);
        __syncthreads();
    }
    if (threadIdx.x == 0) tmax[0] = red[0];
}

// ---------------- TW' = adj ? exp(0.1*(t - tmax)) : 0 ----------------
__global__ __launch_bounds__(256) void ktw(const float* __restrict__ tm, const int* __restrict__ adj,
                                           const float* __restrict__ tmax, float* __restrict__ TW) {
    size_t idx = ((size_t)blockIdx.x * 256 + threadIdx.x) * 4;
    float tmx = tmax[0];
    float4 t = *(const float4*)(tm + idx);
    int4 a = *(const int4*)(adj + idx);
    float4 r;
    r.x = a.x ? __expf(0.1f * (t.x - tmx)) : 0.f;
    r.y = a.y ? __expf(0.1f * (t.y - tmx)) : 0.f;
    r.z = a.z ? __expf(0.1f * (t.z - tmx)) : 0.f;
    r.w = a.w ? __expf(0.1f * (t.w - tmx)) : 0.f;
    *(float4*)(TW + idx) = r;
}

// ---------------- node0 = emb @ struct_W.T + struct_b  (1024 x 512) ----------------
__global__ __launch_bounds__(256) void knode0(const float* __restrict__ emb, const float* __restrict__ sW,
                                              const float* __restrict__ sb, float* __restrict__ node0) {
    int n = blockIdx.x, t = threadIdx.x;
    __shared__ float er[TD];
    if (t < TD) er[t] = emb[n * TD + t];
    __syncthreads();
    for (int k = t; k < HID; k += 256) {
        const float4* w = (const float4*)(sW + (size_t)k * TD);
        float acc = 0.f;
        #pragma unroll
        for (int i = 0; i < TD / 4; i++) {
            float4 wv = w[i];
            float4 ev = *(const float4*)(er + i * 4);
            acc += wv.x * ev.x + wv.y * ev.y + wv.z * ev.z + wv.w * ev.w;
        }
        node0[(size_t)n * HID + k] = acc + sb[k];
    }
}

// ---------------- GEMM: C[b] (Mx512) = A[b] (Mx512) @ W_layer (512x512) ------------
// W is gat_W for one layer: B[i][h*64+o] = W[h*512*64 + i*64 + o]
// 64x64 tile, 4x4 micro. Used for BOTH layers (1024 blocks for layer2 -> 16 waves/CU).
__global__ __launch_bounds__(256) void kgemm64(const float* __restrict__ A, const float* __restrict__ W,
                                               float* __restrict__ C, size_t strideA, size_t strideC) {
    __shared__ float As[32][68];
    __shared__ float Bs[32][64];
    const float* Ab = A + blockIdx.z * strideA;
    float* Cb = C + blockIdx.z * strideC;
    int t = threadIdx.x;
    int tx = t & 15, ty = t >> 4;
    int m0 = blockIdx.y * 64, n0 = blockIdx.x * 64;
    int head = n0 >> 6;
    float acc[4][4] = {};
    for (int k0 = 0; k0 < HID; k0 += 32) {
        #pragma unroll
        for (int r = 0; r < 8; r++) {
            int mm = (t >> 5) + r * 8, kk = t & 31;
            As[kk][mm] = Ab[(size_t)(m0 + mm) * HID + k0 + kk];
        }
        #pragma unroll
        for (int r = 0; r < 8; r++) {
            int nn = t & 63, kk = (t >> 6) + r * 4;
            Bs[kk][nn] = W[(size_t)head * HID * HD + (size_t)(k0 + kk) * HD + nn];
        }
        __syncthreads();
        #pragma unroll
        for (int kk = 0; kk < 32; kk++) {
            float a[4], b[4];
            #pragma unroll
            for (int x = 0; x < 4; x++) a[x] = As[kk][ty * 4 + x];
            #pragma unroll
            for (int x = 0; x < 4; x++) b[x] = Bs[kk][tx * 4 + x];
            #pragma unroll
            for (int y = 0; y < 4; y++)
                #pragma unroll
                for (int x = 0; x < 4; x++) acc[y][x] = fmaf(a[y], b[x], acc[y][x]);
        }
        __syncthreads();
    }
    #pragma unroll
    for (int y = 0; y < 4; y++) {
        int m = m0 + ty * 4 + y;
        #pragma unroll
        for (int x = 0; x < 4; x++) Cb[(size_t)m * HID + n0 + tx * 4 + x] = acc[y][x];
    }
}

// ---------------- e_src / e_dst: one wave per (b,h,n) row ----------------
__global__ __launch_bounds__(256) void kedst(const float* __restrict__ H, const float* __restrict__ ga,
                                             float* __restrict__ es, float* __restrict__ ed, int npairs) {
    int wid = threadIdx.x >> 6, lane = threadIdx.x & 63;
    int p = blockIdx.x * 4 + wid;
    if (p >= npairs) return;
    int n = p & (NT - 1);
    int h = (p >> 10) & (NH - 1);
    int b = p >> 13;
    float v = H[((size_t)(b * NT + n)) * HID + h * HD + lane];
    float s = v * ga[h * 2 * HD + lane];
    float d = v * ga[h * 2 * HD + HD + lane];
    for (int m = 32; m > 0; m >>= 1) { s += __shfl_xor(s, m); d += __shfl_xor(d, m); }
    if (lane == 0) { es[p] = s; ed[p] = d; }
}

// ---------------- layer-1 fused attention as tiled GEMM ----------------
// Block = (h, iblk, b), 256 threads. out(64i x 64o) = P(64i x 1024j) @ H1slice(1024j x 64o).
// P computed on the fly into LDS (transposed: Ps[j][i]); softmax denom via per-thread
// partials reduced once at the end. 4x4 micro per thread.
#define AJC 32
__global__ __launch_bounds__(256) void kattn1(const float* __restrict__ TW, const float* __restrict__ H1,
                                              const float* __restrict__ es, const float* __restrict__ ed,
                                              float* __restrict__ node1) {
    int h = blockIdx.x, iblk = blockIdx.y, b = blockIdx.z;
    int t = threadIdx.x;
    __shared__ float Ps[AJC][68];   // [j][i], 68 pad: rows 16B-aligned for float4 reads
    __shared__ float Hs[AJC][68];   // [j][o]
    __shared__ float es_s[64];
    __shared__ float Ls[64][33];    // row-sum partials [i][jcol]
    __shared__ float invl_s[64];
    int tx = t & 15, ty = t >> 4;
    if (t < 64) es_s[t] = es[h * NT + iblk * 64 + t];
    float lp[8];
    #pragma unroll
    for (int k = 0; k < 8; k++) lp[k] = 0.f;
    float acc[4][4] = {};
    const float* twbase = TW + (size_t)b * NT * NT + (size_t)(iblk * 64) * NT;
    const float* hbase = H1 + h * HD;
    const float* edh = ed + h * NT;
    int pcol = t & 31;       // j within tile (P compute)
    int prow0 = t >> 5;      // i start, step 8
    int hcol = t & 63, hrow0 = t >> 6;  // Hs staging
    __syncthreads();         // es_s ready
    for (int j0 = 0; j0 < NT; j0 += AJC) {
        // global reads first (independent of LDS hazard)
        float hv[8];
        #pragma unroll
        for (int k = 0; k < 8; k++) hv[k] = hbase[(size_t)(j0 + hrow0 + 4 * k) * HID + hcol];
        float edj = edh[j0 + pcol];
        float pv[8];
        #pragma unroll
        for (int k = 0; k < 8; k++) {
            int row = prow0 + 8 * k;
            float tw = twbase[(size_t)row * NT + j0 + pcol];
            float e = es_s[row] + edj;
            e = fmaxf(e, 0.2f * e) * tw;           // leaky_relu then * time weight
            float p = (tw == 0.f) ? 0.f : __expf(e);
            lp[k] += p;
            pv[k] = p;
        }
        __syncthreads();     // previous tile's GEMM reads done
        #pragma unroll
        for (int k = 0; k < 8; k++) Hs[hrow0 + 4 * k][hcol] = hv[k];
        #pragma unroll
        for (int k = 0; k < 8; k++) Ps[pcol][prow0 + 8 * k] = pv[k];
        __syncthreads();
        #pragma unroll
        for (int kk = 0; kk < AJC; kk++) {
            float4 a4 = *(const float4*)&Ps[kk][ty * 4];
            float4 b4 = *(const float4*)&Hs[kk][tx * 4];
            float a[4] = {a4.x, a4.y, a4.z, a4.w};
            float bb[4] = {b4.x, b4.y, b4.z, b4.w};
            #pragma unroll
            for (int y = 0; y < 4; y++)
                #pragma unroll
                for (int x = 0; x < 4; x++) acc[y][x] = fmaf(a[y], bb[x], acc[y][x]);
        }
    }
    // softmax denominator reduction
    #pragma unroll
    for (int k = 0; k < 8; k++) Ls[prow0 + 8 * k][pcol] = lp[k];
    __syncthreads();
    if (t < 64) {
        float s = 0.f;
        #pragma unroll
        for (int c = 0; c < 32; c++) s += Ls[t][c];
        invl_s[t] = 1.f / s;
    }
    __syncthreads();
    float* outb = node1 + ((size_t)(b * NT + iblk * 64)) * HID + h * HD;
    #pragma unroll
    for (int y = 0; y < 4; y++) {
        int row = ty * 4 + y;
        float il = invl_s[row];
        float4 o4;
        float v;
        v = acc[y][0] * il; o4.x = v > 0.f ? v : (__expf(v) - 1.f);
        v = acc[y][1] * il; o4.y = v > 0.f ? v : (__expf(v) - 1.f);
        v = acc[y][2] * il; o4.z = v > 0.f ? v : (__expf(v) - 1.f);
        v = acc[y][3] * il; o4.w = v > 0.f ? v : (__expf(v) - 1.f);
        *(float4*)(outb + (size_t)row * HID + tx * 4) = o4;
    }
}

// ---------------- layer-2 attention at the 8 gathered rows only ----------------
__global__ __launch_bounds__(256) void kattn2(const float* __restrict__ TW, const float* __restrict__ H2,
                                              const float* __restrict__ es, const float* __restrict__ ed,
                                              const int* __restrict__ topic_ids, float* __restrict__ feat) {
    int h = blockIdx.x, b = blockIdx.y;
    int t = threadIdx.x;
    __shared__ float pls[NT];
    __shared__ float red[256];
    int qi = topic_ids[b];
    float esq = es[(b * NH + h) * NT + qi];
    const float* twrow = TW + (size_t)b * NT * NT + (size_t)qi * NT;
    float lsum = 0.f;
    for (int j = t; j < NT; j += 256) {
        float tw = twrow[j];
        float e = esq + ed[(b * NH + h) * NT + j];
        e = fmaxf(e, 0.2f * e) * tw;
        float p = (tw == 0.f) ? 0.f : __expf(e);
        pls[j] = p;
        lsum += p;
    }
    red[t] = lsum; __syncthreads();
    for (int s = 128; s > 0; s >>= 1) { if (t < s) red[t] += red[t + s]; __syncthreads(); }
    float invl = 1.f / red[0];
    int o = t & 63, q = t >> 6;
    float acc = 0.f;
    for (int j = q * 256; j < q * 256 + 256; j++)
        acc = fmaf(pls[j], H2[((size_t)(b * NT) + j) * HID + h * HD + o], acc);
    __syncthreads();
    red[t] = acc; __syncthreads();
    if (t < 64) {
        float v = (red[t] + red[t + 64] + red[t + 128] + red[t + 192]) * invl;
        v = v > 0.f ? v : (__expf(v) - 1.f);  // ELU
        feat[b * HID + h * HD + t] = v;
    }
}

// ---------------- final head: combined -> fc1 relu -> fc2 ----------------
__global__ __launch_bounds__(256) void khead(const float* __restrict__ feat, const float* __restrict__ attr,
                                             const float* __restrict__ aW, const float* __restrict__ ab,
                                             const float* __restrict__ fc1W, const float* __restrict__ fc1b,
                                             const float* __restrict__ fc2W, const float* __restrict__ fc2b,
                                             float* __restrict__ out) {
    int b = blockIdx.x, t = threadIdx.x;
    __shared__ float comb[HID];
    __shared__ float red[256];
    float av = attr[b];
    for (int k = t; k < HID; k += 256) comb[k] = feat[b * HID + k] + av * aW[k] + ab[k];
    __syncthreads();
    float part = 0.f;
    for (int k = t; k < HID; k += 256) {
        const float4* wr = (const float4*)(fc1W + (size_t)k * HID);
        float acc = 0.f;
        #pragma unroll 4
        for (int m = 0; m < HID / 4; m++) {
            float4 w4 = wr[m];
            float4 c4 = *(const float4*)(comb + m * 4);
            acc += w4.x * c4.x + w4.y * c4.y + w4.z * c4.z + w4.w * c4.w;
        }
        float hk = fmaxf(acc + fc1b[k], 0.f);
        part = fmaf(hk, fc2W[k], part);
    }
    red[t] = part; __syncthreads();
    for (int s = 128; s > 0; s >>= 1) { if (t < s) red[t] += red[t + s]; __syncthreads(); }
    if (t == 0) out[b] = red[0] + fc2b[0];
}

extern "C" void kernel_launch(void* const* d_in, const int* in_sizes, int n_in,
                              void* d_out, int out_size, void* d_ws, size_t ws_size,
                              hipStream_t stream) {
    const int*   topic_ids = (const int*)d_in[0];
    const int*   adj       = (const int*)d_in[1];
    const float* tm        = (const float*)d_in[2];
    const float* attr      = (const float*)d_in[3];
    const float* emb       = (const float*)d_in[4];
    const float* sW        = (const float*)d_in[5];
    const float* sb        = (const float*)d_in[6];
    const float* aW        = (const float*)d_in[7];
    const float* ab        = (const float*)d_in[8];
    const float* gW        = (const float*)d_in[9];   // (2,8,512,64)
    const float* ga        = (const float*)d_in[10];  // (2,8,128,1)
    const float* fc1W      = (const float*)d_in[11];
    const float* fc1b      = (const float*)d_in[12];
    const float* fc2W      = (const float*)d_in[13];
    const float* fc2b      = (const float*)d_in[14];
    float* out = (float*)d_out;

    float* ws    = (float*)d_ws;
    float* TW    = ws;                      // 8 M
    float* node0 = TW    + (size_t)NB * NT * NT;   // 512 K
    float* H1    = node0 + (size_t)NT * HID;       // 512 K
    float* node1 = H1    + (size_t)NT * HID;       // 4 M
    float* H2    = node1 + (size_t)NB * NT * HID;  // 4 M
    float* es1   = H2    + (size_t)NB * NT * HID;  // 8 K
    float* ed1   = es1 + NH * NT;
    float* es2   = ed1 + NH * NT;                  // 64 K
    float* ed2   = es2 + NB * NH * NT;
    float* feat  = ed2 + NB * NH * NT;             // 4 K
    float* part  = feat + NB * HID;
    float* tmax  = part + 1024;

    kmax1<<<1024, 256, 0, stream>>>(tm, part);
    kmax2<<<1, 256, 0, stream>>>(part, tmax);
    ktw<<<(NB * NT * NT) / 1024, 256, 0, stream>>>(tm, adj, tmax, TW);
    knode0<<<NT, 256, 0, stream>>>(emb, sW, sb, node0);
    // layer 1: h (batch-shared)
    kgemm64<<<dim3(HID / 64, NT / 64, 1), 256, 0, stream>>>(node0, gW, H1, 0, 0);
    kedst<<<(NH * NT) / 4, 256, 0, stream>>>(H1, ga, es1, ed1, NH * NT);
    kattn1<<<dim3(NH, NT / 64, NB), 256, 0, stream>>>(TW, H1, es1, ed1, node1);
    // layer 2: h per batch (1024 blocks -> 16 waves/CU)
    kgemm64<<<dim3(HID / 64, NT / 64, NB), 256, 0, stream>>>(node1, gW + 8 * 512 * 64, H2,
                                                             (size_t)NT * HID, (size_t)NT * HID);
    kedst<<<(NB * NH * NT) / 4, 256, 0, stream>>>(H2, ga + 8 * 128, es2, ed2, NB * NH * NT);
    kattn2<<<dim3(NH, NB), 256, 0, stream>>>(TW, H2, es2, ed2, topic_ids, feat);
    khead<<<NB, 256, 0, stream>>>(feat, attr, aW, ab, fc1W, fc1b, fc2W, fc2b, out);
}

// Round 3
// 389.409 us; speedup vs baseline: 2.0355x; 1.3108x over previous
//
#include <hip/hip_runtime.h>

// Sizes
#define NT 1024      // N_TOPICS
#define TD 128       // TOPIC_DIM
#define HID 512      // HIDDEN
#define NH 8         // N_HEADS
#define HD 64        // HEAD_DIM
#define NB 8         // BATCH

typedef short bf16x8 __attribute__((ext_vector_type(8)));
typedef float f32x4 __attribute__((ext_vector_type(4)));

__device__ __forceinline__ unsigned short f2bf(float x) {
    unsigned int u = __float_as_uint(x);
    unsigned int r = (u + 0x7FFFu + ((u >> 16) & 1u)) >> 16;
    return (unsigned short)r;
}

// ---------------- time max reduction ----------------
__global__ __launch_bounds__(256) void kmax1(const float* __restrict__ tm, float* __restrict__ part) {
    int idx = blockIdx.x * 256 + threadIdx.x;
    float m = -1e30f;
    for (size_t i = idx; i < (size_t)NB * NT * NT; i += 1024 * 256) m = fmaxf(m, tm[i]);
    __shared__ float red[256];
    red[threadIdx.x] = m; __syncthreads();
    for (int s = 128; s > 0; s >>= 1) {
        if (threadIdx.x < s) red[threadIdx.x] = fmaxf(red[threadIdx.x], red[threadIdx.x + s]);
        __syncthreads();
    }
    if (threadIdx.x == 0) part[blockIdx.x] = red[0];
}

__global__ __launch_bounds__(256) void kmax2(const float* __restrict__ part, float* __restrict__ tmax) {
    float m = -1e30f;
    for (int i = threadIdx.x; i < 1024; i += 256) m = fmaxf(m, part[i]);
    __shared__ float red[256];
    red[threadIdx.x] = m; __syncthreads();
    for (int s = 128; s > 0; s >>= 1) {
        if (threadIdx.x < s) red[threadIdx.x] = fmaxf(red[threadIdx.x], red[threadIdx.x + s]);
        __syncthreads();
    }
    if (threadIdx.x == 0) tmax[0] = red[0];
}

// ---------------- TW' = adj ? exp(0.1*(t - tmax)) : 0 ----------------
__global__ __launch_bounds__(256) void ktw(const float* __restrict__ tm, const int* __restrict__ adj,
                                           const float* __restrict__ tmax, float* __restrict__ TW) {
    size_t idx = ((size_t)blockIdx.x * 256 + threadIdx.x) * 4;
    float tmx = tmax[0];
    float4 t = *(const float4*)(tm + idx);
    int4 a = *(const int4*)(adj + idx);
    float4 r;
    r.x = a.x ? __expf(0.1f * (t.x - tmx)) : 0.f;
    r.y = a.y ? __expf(0.1f * (t.y - tmx)) : 0.f;
    r.z = a.z ? __expf(0.1f * (t.z - tmx)) : 0.f;
    r.w = a.w ? __expf(0.1f * (t.w - tmx)) : 0.f;
    *(float4*)(TW + idx) = r;
}

// ---------------- Wt[l][h][o][k] = bf16(gat_W[l][h][k][o]) ----------------
__global__ __launch_bounds__(256) void kcvt(const float* __restrict__ gW, unsigned short* __restrict__ Wt) {
    int lh = blockIdx.x;  // 0..15 = l*8+h
    const float* src = gW + (size_t)lh * HID * HD;
    unsigned short* dst = Wt + (size_t)lh * HD * HID;
    for (int idx = threadIdx.x; idx < HID * HD; idx += 256) {
        int k = idx >> 6, o = idx & 63;
        dst[o * HID + k] = f2bf(src[idx]);
    }
}

// ---------------- node0_bf16 = bf16(emb @ struct_W.T + struct_b) ----------------
__global__ __launch_bounds__(256) void knode0(const float* __restrict__ emb, const float* __restrict__ sW,
                                              const float* __restrict__ sb, unsigned short* __restrict__ node0b) {
    int n = blockIdx.x, t = threadIdx.x;
    __shared__ float er[TD];
    if (t < TD) er[t] = emb[n * TD + t];
    __syncthreads();
    for (int k = t; k < HID; k += 256) {
        const float4* w = (const float4*)(sW + (size_t)k * TD);
        float acc = 0.f;
        #pragma unroll
        for (int i = 0; i < TD / 4; i++) {
            float4 wv = w[i];
            float4 ev = *(const float4*)(er + i * 4);
            acc += wv.x * ev.x + wv.y * ev.y + wv.z * ev.z + wv.w * ev.w;
        }
        node0b[(size_t)n * HID + k] = f2bf(acc + sb[k]);
    }
}

// ---------------- bf16 MFMA GEMM: H = A(bf16) @ W(bf16), out fp32 (+opt transposed bf16) --
// grid: (x = iblk + 16*b, y = h). Block 256 = 4 waves; wave w owns i-strip w*16.
// A: [b*1024 + i][512] bf16. Wt: [(h*64+o)][512] bf16. outF: fp32 [b*1024+i][512].
// outT (may be null): bf16 [(h*64+o)][1024] transposed copy (for attention B-frags).
__global__ __launch_bounds__(256) void kgemm_mfma(const unsigned short* __restrict__ A,
                                                  const unsigned short* __restrict__ Wt,
                                                  float* __restrict__ outF,
                                                  unsigned short* __restrict__ outT) {
    int x = blockIdx.x; int iblk = x & 15; int b = x >> 4; int h = blockIdx.y;
    int t = threadIdx.x;
    __shared__ __align__(16) unsigned short As[64 * 40];   // [i][k] stride 40 halves (16B-aligned rows)
    __shared__ __align__(16) unsigned short Bs[64 * 40];   // [o][k]
    int l = t & 63, w = t >> 6, m = l & 15, q = l >> 4;
    int r = t >> 2, c = t & 3;
    size_t arow0 = (size_t)(b * NT + iblk * 64);
    f32x4 acc[4];
    #pragma unroll
    for (int ot = 0; ot < 4; ot++) acc[ot] = (f32x4){0.f, 0.f, 0.f, 0.f};
    for (int k0 = 0; k0 < HID; k0 += 32) {
        uint4 av = *(const uint4*)&A[(arow0 + r) * HID + k0 + c * 8];
        uint4 bv = *(const uint4*)&Wt[(size_t)(h * HD + r) * HID + k0 + c * 8];
        *(uint4*)&As[r * 40 + c * 8] = av;
        *(uint4*)&Bs[r * 40 + c * 8] = bv;
        __syncthreads();
        bf16x8 a = *(const bf16x8*)&As[(w * 16 + m) * 40 + q * 8];
        #pragma unroll
        for (int ot = 0; ot < 4; ot++) {
            bf16x8 bb = *(const bf16x8*)&Bs[(ot * 16 + m) * 40 + q * 8];
            acc[ot] = __builtin_amdgcn_mfma_f32_16x16x32_bf16(a, bb, acc[ot], 0, 0, 0);
        }
        __syncthreads();
    }
    #pragma unroll
    for (int ot = 0; ot < 4; ot++) {
        int col = h * HD + ot * 16 + m;
        #pragma unroll
        for (int rr = 0; rr < 4; rr++) {
            int i_loc = w * 16 + q * 4 + rr;
            float v = acc[ot][rr];
            outF[(arow0 + i_loc) * HID + col] = v;
            if (outT) outT[(size_t)col * NT + iblk * 64 + i_loc] = f2bf(v);
        }
    }
}

// ---------------- e_src / e_dst: one wave per (b,h,n) row ----------------
__global__ __launch_bounds__(256) void kedst(const float* __restrict__ H, const float* __restrict__ ga,
                                             float* __restrict__ es, float* __restrict__ ed, int npairs) {
    int wid = threadIdx.x >> 6, lane = threadIdx.x & 63;
    int p = blockIdx.x * 4 + wid;
    if (p >= npairs) return;
    int n = p & (NT - 1);
    int h = (p >> 10) & (NH - 1);
    int b = p >> 13;
    float v = H[((size_t)(b * NT + n)) * HID + h * HD + lane];
    float s = v * ga[h * 2 * HD + lane];
    float d = v * ga[h * 2 * HD + HD + lane];
    for (int m = 32; m > 0; m >>= 1) { s += __shfl_xor(s, m); d += __shfl_xor(d, m); }
    if (lane == 0) { es[p] = s; ed[p] = d; }
}

// ---------------- layer-1 fused attention: P on the fly -> bf16 MFMA PV ----------------
// grid (x = iblk + 16*b, y = h): the 8 head-blocks of one TW tile have consecutive
// blockIdx -> same XCD (mod-8 round robin) -> TW tile L2-resident across heads.
// P compute: thread t owns (i = t>>2, 8 j at (t&3)*8): coalesced TW row reads,
// uniform-bank stride-20dw LDS writes. PV: 4 waves x 4 MFMA tiles, K = j.
__global__ __launch_bounds__(256) void kattn1(const float* __restrict__ TW, const unsigned short* __restrict__ Ht,
                                              const float* __restrict__ es, const float* __restrict__ ed,
                                              unsigned short* __restrict__ node1b) {
    int x = blockIdx.x; int iblk = x & 15; int b = x >> 4; int h = blockIdx.y;
    int t = threadIdx.x;
    __shared__ __align__(16) unsigned short Ps[64 * 40];   // [i][j] bf16
    __shared__ __align__(16) unsigned short Hs[64 * 40];   // [o][j] bf16
    __shared__ float Ls[64 * 5];
    __shared__ float invl_s[64];
    int i = t >> 2, jc = t & 3;
    int l = t & 63, w = t >> 6, m = l & 15, q = l >> 4;
    float es_i = es[h * NT + iblk * 64 + i];
    const float* twrow = TW + (size_t)b * NT * NT + (size_t)(iblk * 64 + i) * NT;
    const float* edh = ed + h * NT;
    const unsigned short* htrow = Ht + (size_t)(h * HD + i) * NT;  // staging row o == i
    f32x4 acc[4];
    #pragma unroll
    for (int ot = 0; ot < 4; ot++) acc[ot] = (f32x4){0.f, 0.f, 0.f, 0.f};
    float lp = 0.f;
    for (int j0 = 0; j0 < NT; j0 += 32) {
        float4 t0 = *(const float4*)&twrow[j0 + jc * 8];
        float4 t1 = *(const float4*)&twrow[j0 + jc * 8 + 4];
        float4 e0 = *(const float4*)&edh[j0 + jc * 8];
        float4 e1 = *(const float4*)&edh[j0 + jc * 8 + 4];
        uint4 hv = *(const uint4*)&htrow[j0 + jc * 8];
        float twv[8] = {t0.x, t0.y, t0.z, t0.w, t1.x, t1.y, t1.z, t1.w};
        float edv[8] = {e0.x, e0.y, e0.z, e0.w, e1.x, e1.y, e1.z, e1.w};
        unsigned int pk[4];
        #pragma unroll
        for (int jj = 0; jj < 4; jj++) {
            float ea = es_i + edv[2 * jj];
            ea = fmaxf(ea, 0.2f * ea) * twv[2 * jj];
            float pa = (twv[2 * jj] == 0.f) ? 0.f : __expf(ea);
            float eb = es_i + edv[2 * jj + 1];
            eb = fmaxf(eb, 0.2f * eb) * twv[2 * jj + 1];
            float pb = (twv[2 * jj + 1] == 0.f) ? 0.f : __expf(eb);
            lp += pa + pb;
            pk[jj] = (unsigned int)f2bf(pa) | ((unsigned int)f2bf(pb) << 16);
        }
        __syncthreads();   // previous tile's MFMA frag reads done
        *(uint4*)&Ps[i * 40 + jc * 8] = make_uint4(pk[0], pk[1], pk[2], pk[3]);
        *(uint4*)&Hs[i * 40 + jc * 8] = hv;
        __syncthreads();
        bf16x8 a = *(const bf16x8*)&Ps[(w * 16 + m) * 40 + q * 8];
        #pragma unroll
        for (int ot = 0; ot < 4; ot++) {
            bf16x8 bb = *(const bf16x8*)&Hs[(ot * 16 + m) * 40 + q * 8];
            acc[ot] = __builtin_amdgcn_mfma_f32_16x16x32_bf16(a, bb, acc[ot], 0, 0, 0);
        }
    }
    Ls[i * 5 + jc] = lp;
    __syncthreads();
    if (t < 64) {
        float s = Ls[t * 5] + Ls[t * 5 + 1] + Ls[t * 5 + 2] + Ls[t * 5 + 3];
        invl_s[t] = 1.f / s;
    }
    __syncthreads();
    #pragma unroll
    for (int ot = 0; ot < 4; ot++) {
        int col = h * HD + ot * 16 + m;
        #pragma unroll
        for (int rr = 0; rr < 4; rr++) {
            int i_loc = w * 16 + q * 4 + rr;
            float v = acc[ot][rr] * invl_s[i_loc];
            v = v > 0.f ? v : (__expf(v) - 1.f);  // ELU
            node1b[(size_t)(b * NT + iblk * 64 + i_loc) * HID + col] = f2bf(v);
        }
    }
}

// ---------------- layer-2 attention at the 8 gathered rows only ----------------
__global__ __launch_bounds__(256) void kattn2(const float* __restrict__ TW, const float* __restrict__ H2,
                                              const float* __restrict__ es, const float* __restrict__ ed,
                                              const int* __restrict__ topic_ids, float* __restrict__ feat) {
    int h = blockIdx.x, b = blockIdx.y;
    int t = threadIdx.x;
    __shared__ float pls[NT];
    __shared__ float red[256];
    int qi = topic_ids[b];
    float esq = es[(b * NH + h) * NT + qi];
    const float* twrow = TW + (size_t)b * NT * NT + (size_t)qi * NT;
    float lsum = 0.f;
    for (int j = t; j < NT; j += 256) {
        float tw = twrow[j];
        float e = esq + ed[(b * NH + h) * NT + j];
        e = fmaxf(e, 0.2f * e) * tw;
        float p = (tw == 0.f) ? 0.f : __expf(e);
        pls[j] = p;
        lsum += p;
    }
    red[t] = lsum; __syncthreads();
    for (int s = 128; s > 0; s >>= 1) { if (t < s) red[t] += red[t + s]; __syncthreads(); }
    float invl = 1.f / red[0];
    int o = t & 63, qq = t >> 6;
    float acc = 0.f;
    for (int j = qq * 256; j < qq * 256 + 256; j++)
        acc = fmaf(pls[j], H2[((size_t)(b * NT) + j) * HID + h * HD + o], acc);
    __syncthreads();
    red[t] = acc; __syncthreads();
    if (t < 64) {
        float v = (red[t] + red[t + 64] + red[t + 128] + red[t + 192]) * invl;
        v = v > 0.f ? v : (__expf(v) - 1.f);  // ELU
        feat[b * HID + h * HD + t] = v;
    }
}

// ---------------- final head: combined -> fc1 relu -> fc2 ----------------
__global__ __launch_bounds__(256) void khead(const float* __restrict__ feat, const float* __restrict__ attr,
                                             const float* __restrict__ aW, const float* __restrict__ ab,
                                             const float* __restrict__ fc1W, const float* __restrict__ fc1b,
                                             const float* __restrict__ fc2W, const float* __restrict__ fc2b,
                                             float* __restrict__ out) {
    int b = blockIdx.x, t = threadIdx.x;
    __shared__ float comb[HID];
    __shared__ float red[256];
    float av = attr[b];
    for (int k = t; k < HID; k += 256) comb[k] = feat[b * HID + k] + av * aW[k] + ab[k];
    __syncthreads();
    float part = 0.f;
    for (int k = t; k < HID; k += 256) {
        const float4* wr = (const float4*)(fc1W + (size_t)k * HID);
        float acc = 0.f;
        #pragma unroll 4
        for (int m = 0; m < HID / 4; m++) {
            float4 w4 = wr[m];
            float4 c4 = *(const float4*)(comb + m * 4);
            acc += w4.x * c4.x + w4.y * c4.y + w4.z * c4.z + w4.w * c4.w;
        }
        float hk = fmaxf(acc + fc1b[k], 0.f);
        part = fmaf(hk, fc2W[k], part);
    }
    red[t] = part; __syncthreads();
    for (int s = 128; s > 0; s >>= 1) { if (t < s) red[t] += red[t + s]; __syncthreads(); }
    if (t == 0) out[b] = red[0] + fc2b[0];
}

extern "C" void kernel_launch(void* const* d_in, const int* in_sizes, int n_in,
                              void* d_out, int out_size, void* d_ws, size_t ws_size,
                              hipStream_t stream) {
    const int*   topic_ids = (const int*)d_in[0];
    const int*   adj       = (const int*)d_in[1];
    const float* tm        = (const float*)d_in[2];
    const float* attr      = (const float*)d_in[3];
    const float* emb       = (const float*)d_in[4];
    const float* sW        = (const float*)d_in[5];
    const float* sb        = (const float*)d_in[6];
    const float* aW        = (const float*)d_in[7];
    const float* ab        = (const float*)d_in[8];
    const float* gW        = (const float*)d_in[9];   // (2,8,512,64)
    const float* ga        = (const float*)d_in[10];  // (2,8,128,1)
    const float* fc1W      = (const float*)d_in[11];
    const float* fc1b      = (const float*)d_in[12];
    const float* fc2W      = (const float*)d_in[13];
    const float* fc2b      = (const float*)d_in[14];
    float* out = (float*)d_out;

    char* p = (char*)d_ws;
    float* TW       = (float*)p;            p += sizeof(float) * (size_t)NB * NT * NT;   // 33.5 MB
    float* H1       = (float*)p;            p += sizeof(float) * (size_t)NT * HID;       // 2 MB
    float* H2       = (float*)p;            p += sizeof(float) * (size_t)NB * NT * HID;  // 16 MB
    unsigned short* node0b = (unsigned short*)p; p += sizeof(short) * (size_t)NT * HID;  // 1 MB
    unsigned short* Wt     = (unsigned short*)p; p += sizeof(short) * (size_t)2 * NH * HD * HID; // 1 MB
    unsigned short* Ht1    = (unsigned short*)p; p += sizeof(short) * (size_t)HID * NT;  // 1 MB
    unsigned short* node1b = (unsigned short*)p; p += sizeof(short) * (size_t)NB * NT * HID; // 8 MB
    float* es1      = (float*)p;            p += sizeof(float) * NH * NT;
    float* ed1      = (float*)p;            p += sizeof(float) * NH * NT;
    float* es2      = (float*)p;            p += sizeof(float) * NB * NH * NT;
    float* ed2      = (float*)p;            p += sizeof(float) * NB * NH * NT;
    float* feat     = (float*)p;            p += sizeof(float) * NB * HID;
    float* part     = (float*)p;            p += sizeof(float) * 1024;
    float* tmax     = (float*)p;            p += sizeof(float);

    kmax1<<<1024, 256, 0, stream>>>(tm, part);
    kmax2<<<1, 256, 0, stream>>>(part, tmax);
    ktw<<<(NB * NT * NT) / 1024, 256, 0, stream>>>(tm, adj, tmax, TW);
    kcvt<<<16, 256, 0, stream>>>(gW, Wt);
    knode0<<<NT, 256, 0, stream>>>(emb, sW, sb, node0b);
    // layer 1 (batch-shared): H1 fp32 + transposed bf16 Ht1
    kgemm_mfma<<<dim3(16, NH), 256, 0, stream>>>(node0b, Wt, H1, Ht1);
    kedst<<<(NH * NT) / 4, 256, 0, stream>>>(H1, ga, es1, ed1, NH * NT);
    kattn1<<<dim3(16 * NB, NH), 256, 0, stream>>>(TW, Ht1, es1, ed1, node1b);
    // layer 2: per batch
    kgemm_mfma<<<dim3(16 * NB, NH), 256, 0, stream>>>(node1b, Wt + (size_t)NH * HD * HID, H2, nullptr);
    kedst<<<(NB * NH * NT) / 4, 256, 0, stream>>>(H2, ga + NH * 2 * HD, es2, ed2, NB * NH * NT);
    kattn2<<<dim3(NH, NB), 256, 0, stream>>>(TW, H2, es2, ed2, topic_ids, feat);
    khead<<<NB, 256, 0, stream>>>(feat, attr, aW, ab, fc1W, fc1b, fc2W, fc2b, out);
}

// Round 4
// 288.210 us; speedup vs baseline: 2.7503x; 1.3511x over previous
//
#include <hip/hip_runtime.h>

// Sizes
#define NT 1024      // N_TOPICS
#define TD 128       // TOPIC_DIM
#define HID 512      // HIDDEN
#define NH 8         // N_HEADS
#define HD 64        // HEAD_DIM
#define NB 8         // BATCH

typedef short bf16x8 __attribute__((ext_vector_type(8)));
typedef float f32x4 __attribute__((ext_vector_type(4)));

__device__ __forceinline__ unsigned short f2bf(float x) {
    unsigned int u = __float_as_uint(x);
    return (unsigned short)((u + 0x7FFFu + ((u >> 16) & 1u)) >> 16);
}
__device__ __forceinline__ float bf2f(unsigned short s) {
    return __uint_as_float(((unsigned int)s) << 16);
}

// ---------------- time max partial reduction ----------------
__global__ __launch_bounds__(256) void kmax1(const float* __restrict__ tm, float* __restrict__ part) {
    int idx = blockIdx.x * 256 + threadIdx.x;
    float m = -1e30f;
    for (size_t i = idx; i < (size_t)NB * NT * NT; i += 1024 * 256) m = fmaxf(m, tm[i]);
    __shared__ float red[256];
    red[threadIdx.x] = m; __syncthreads();
    for (int s = 128; s > 0; s >>= 1) {
        if (threadIdx.x < s) red[threadIdx.x] = fmaxf(red[threadIdx.x], red[threadIdx.x + s]);
        __syncthreads();
    }
    if (threadIdx.x == 0) part[blockIdx.x] = red[0];
}

// ---------------- TWb = bf16(adj ? exp(0.1*(t - tmax)) : 0); final max folded in ------
__global__ __launch_bounds__(256) void ktw(const float* __restrict__ tm, const int* __restrict__ adj,
                                           const float* __restrict__ part, unsigned short* __restrict__ TWb) {
    __shared__ float red[256];
    int t = threadIdx.x;
    float m = fmaxf(fmaxf(part[t * 4], part[t * 4 + 1]), fmaxf(part[t * 4 + 2], part[t * 4 + 3]));
    red[t] = m; __syncthreads();
    for (int s = 128; s > 0; s >>= 1) {
        if (t < s) red[t] = fmaxf(red[t], red[t + s]);
        __syncthreads();
    }
    float tmx = red[0];
    #pragma unroll
    for (int it = 0; it < 4; it++) {
        size_t idx = (((size_t)blockIdx.x * 4 + it) * 256 + t) * 4;
        float4 tv = *(const float4*)(tm + idx);
        int4 av = *(const int4*)(adj + idx);
        unsigned int r0 = av.x ? f2bf(__expf(0.1f * (tv.x - tmx))) : 0u;
        unsigned int r1 = av.y ? f2bf(__expf(0.1f * (tv.y - tmx))) : 0u;
        unsigned int r2 = av.z ? f2bf(__expf(0.1f * (tv.z - tmx))) : 0u;
        unsigned int r3 = av.w ? f2bf(__expf(0.1f * (tv.w - tmx))) : 0u;
        uint2 pk;
        pk.x = r0 | (r1 << 16);
        pk.y = r2 | (r3 << 16);
        *(uint2*)&TWb[idx] = pk;
    }
}

// ---------------- Wt[l][h][o][k] = bf16(gat_W[l][h][k][o]) ----------------
__global__ __launch_bounds__(256) void kcvt(const float* __restrict__ gW, unsigned short* __restrict__ Wt) {
    int lh = blockIdx.x >> 3, seg = blockIdx.x & 7;
    const float* src = gW + (size_t)lh * HID * HD;
    unsigned short* dst = Wt + (size_t)lh * HD * HID;
    for (int idx = seg * 4096 + threadIdx.x; idx < (seg + 1) * 4096; idx += 256) {
        int k = idx >> 6, o = idx & 63;
        dst[o * HID + k] = f2bf(src[idx]);
    }
}

// ---------------- node0_bf16 = bf16(emb @ struct_W.T + struct_b) ----------------
__global__ __launch_bounds__(256) void knode0(const float* __restrict__ emb, const float* __restrict__ sW,
                                              const float* __restrict__ sb, unsigned short* __restrict__ node0b) {
    int n = blockIdx.x, t = threadIdx.x;
    __shared__ float er[TD];
    if (t < TD) er[t] = emb[n * TD + t];
    __syncthreads();
    for (int k = t; k < HID; k += 256) {
        const float4* w = (const float4*)(sW + (size_t)k * TD);
        float acc = 0.f;
        #pragma unroll
        for (int i = 0; i < TD / 4; i++) {
            float4 wv = w[i];
            float4 ev = *(const float4*)(er + i * 4);
            acc += wv.x * ev.x + wv.y * ev.y + wv.z * ev.z + wv.w * ev.w;
        }
        node0b[(size_t)n * HID + k] = f2bf(acc + sb[k]);
    }
}

// ---------------- bf16 MFMA GEMM + fused e_src/e_dst epilogue ----------------
// grid: (x = iblk + 16*b, y = h). A: [b*1024+i][512] bf16. Wt: [(h*64+o)][512] bf16.
// outT (opt): bf16 [(h*64+o)][1024]. outR (opt): bf16 [b*1024+i][512].
// esO/edO: fp32 [(b*8+h)*1024 + i] per-row attention scalars (from fp32 accs).
__global__ __launch_bounds__(256) void kgemm_mfma(const unsigned short* __restrict__ A,
                                                  const unsigned short* __restrict__ Wt,
                                                  const float* __restrict__ gav,
                                                  unsigned short* __restrict__ outT,
                                                  unsigned short* __restrict__ outR,
                                                  float* __restrict__ esO, float* __restrict__ edO) {
    int x = blockIdx.x; int iblk = x & 15; int b = x >> 4; int h = blockIdx.y;
    int t = threadIdx.x;
    __shared__ __align__(16) unsigned short As[64 * 40];
    __shared__ __align__(16) unsigned short Bs[64 * 40];
    int l = t & 63, w = t >> 6, m = l & 15, q = l >> 4;
    int r = t >> 2, c = t & 3;
    size_t arow0 = (size_t)(b * NT + iblk * 64);
    f32x4 acc[4];
    #pragma unroll
    for (int ot = 0; ot < 4; ot++) acc[ot] = (f32x4){0.f, 0.f, 0.f, 0.f};
    for (int k0 = 0; k0 < HID; k0 += 32) {
        uint4 av = *(const uint4*)&A[(arow0 + r) * HID + k0 + c * 8];
        uint4 bv = *(const uint4*)&Wt[(size_t)(h * HD + r) * HID + k0 + c * 8];
        *(uint4*)&As[r * 40 + c * 8] = av;
        *(uint4*)&Bs[r * 40 + c * 8] = bv;
        __syncthreads();
        bf16x8 a = *(const bf16x8*)&As[(w * 16 + m) * 40 + q * 8];
        #pragma unroll
        for (int ot = 0; ot < 4; ot++) {
            bf16x8 bb = *(const bf16x8*)&Bs[(ot * 16 + m) * 40 + q * 8];
            acc[ot] = __builtin_amdgcn_mfma_f32_16x16x32_bf16(a, bb, acc[ot], 0, 0, 0);
        }
        __syncthreads();
    }
    // fused e_src/e_dst: per-row dot with a_src/a_dst over this head's 64 cols
    const float* gas = gav + h * 2 * HD;
    float gs[4], gd[4];
    #pragma unroll
    for (int ot = 0; ot < 4; ot++) { gs[ot] = gas[ot * 16 + m]; gd[ot] = gas[HD + ot * 16 + m]; }
    size_t ebase = ((size_t)b * NH + h) * NT + iblk * 64;
    #pragma unroll
    for (int rr = 0; rr < 4; rr++) {
        float s = 0.f, d = 0.f;
        #pragma unroll
        for (int ot = 0; ot < 4; ot++) { float v = acc[ot][rr]; s = fmaf(v, gs[ot], s); d = fmaf(v, gd[ot], d); }
        #pragma unroll
        for (int mask = 1; mask < 16; mask <<= 1) { s += __shfl_xor(s, mask); d += __shfl_xor(d, mask); }
        if (m == 0) {
            int row = w * 16 + q * 4 + rr;
            esO[ebase + row] = s;
            edO[ebase + row] = d;
        }
    }
    #pragma unroll
    for (int ot = 0; ot < 4; ot++) {
        int col = h * HD + ot * 16 + m;
        #pragma unroll
        for (int rr = 0; rr < 4; rr++) {
            int i_loc = w * 16 + q * 4 + rr;
            float v = acc[ot][rr];
            if (outT) outT[(size_t)col * NT + iblk * 64 + i_loc] = f2bf(v);
            if (outR) outR[(arow0 + i_loc) * HID + col] = f2bf(v);
        }
    }
}

// ---------------- layer-1 fused attention: P on the fly -> bf16 MFMA PV ----------------
__global__ __launch_bounds__(256) void kattn1(const unsigned short* __restrict__ TWb,
                                              const unsigned short* __restrict__ Ht,
                                              const float* __restrict__ es, const float* __restrict__ ed,
                                              unsigned short* __restrict__ node1b) {
    int x = blockIdx.x; int iblk = x & 15; int b = x >> 4; int h = blockIdx.y;
    int t = threadIdx.x;
    __shared__ __align__(16) unsigned short Ps[64 * 40];
    __shared__ __align__(16) unsigned short Hs[64 * 40];
    __shared__ float Ls[64 * 5];
    __shared__ float invl_s[64];
    int i = t >> 2, jc = t & 3;
    int l = t & 63, w = t >> 6, m = l & 15, q = l >> 4;
    float es_i = es[h * NT + iblk * 64 + i];
    const unsigned short* twrow = TWb + (size_t)b * NT * NT + (size_t)(iblk * 64 + i) * NT;
    const float* edh = ed + h * NT;
    const unsigned short* htrow = Ht + (size_t)(h * HD + i) * NT;
    f32x4 acc[4];
    #pragma unroll
    for (int ot = 0; ot < 4; ot++) acc[ot] = (f32x4){0.f, 0.f, 0.f, 0.f};
    float lp = 0.f;
    for (int j0 = 0; j0 < NT; j0 += 32) {
        union { uint4 v; unsigned short u[8]; } twu;
        twu.v = *(const uint4*)&twrow[j0 + jc * 8];
        float4 e0 = *(const float4*)&edh[j0 + jc * 8];
        float4 e1 = *(const float4*)&edh[j0 + jc * 8 + 4];
        uint4 hv = *(const uint4*)&htrow[j0 + jc * 8];
        float edv[8] = {e0.x, e0.y, e0.z, e0.w, e1.x, e1.y, e1.z, e1.w};
        unsigned int pk[4];
        #pragma unroll
        for (int jj = 0; jj < 4; jj++) {
            float twa = bf2f(twu.u[2 * jj]), twb = bf2f(twu.u[2 * jj + 1]);
            float ea = es_i + edv[2 * jj];
            ea = fmaxf(ea, 0.2f * ea) * twa;
            float pa = twu.u[2 * jj] ? __expf(ea) : 0.f;
            float eb = es_i + edv[2 * jj + 1];
            eb = fmaxf(eb, 0.2f * eb) * twb;
            float pb = twu.u[2 * jj + 1] ? __expf(eb) : 0.f;
            lp += pa + pb;
            pk[jj] = (unsigned int)f2bf(pa) | ((unsigned int)f2bf(pb) << 16);
        }
        __syncthreads();
        *(uint4*)&Ps[i * 40 + jc * 8] = make_uint4(pk[0], pk[1], pk[2], pk[3]);
        *(uint4*)&Hs[i * 40 + jc * 8] = hv;
        __syncthreads();
        bf16x8 a = *(const bf16x8*)&Ps[(w * 16 + m) * 40 + q * 8];
        #pragma unroll
        for (int ot = 0; ot < 4; ot++) {
            bf16x8 bb = *(const bf16x8*)&Hs[(ot * 16 + m) * 40 + q * 8];
            acc[ot] = __builtin_amdgcn_mfma_f32_16x16x32_bf16(a, bb, acc[ot], 0, 0, 0);
        }
    }
    Ls[i * 5 + jc] = lp;
    __syncthreads();
    if (t < 64) {
        float s = Ls[t * 5] + Ls[t * 5 + 1] + Ls[t * 5 + 2] + Ls[t * 5 + 3];
        invl_s[t] = 1.f / s;
    }
    __syncthreads();
    #pragma unroll
    for (int ot = 0; ot < 4; ot++) {
        int col = h * HD + ot * 16 + m;
        #pragma unroll
        for (int rr = 0; rr < 4; rr++) {
            int i_loc = w * 16 + q * 4 + rr;
            float v = acc[ot][rr] * invl_s[i_loc];
            v = v > 0.f ? v : (__expf(v) - 1.f);  // ELU
            node1b[(size_t)(b * NT + iblk * 64 + i_loc) * HID + col] = f2bf(v);
        }
    }
}

// ---------------- layer-2 attention phase A: partial PV over 64-j slices ----------------
// grid (js=16, h=8, b=8) = 1024 blocks.
__global__ __launch_bounds__(256) void kattn2a(const unsigned short* __restrict__ TWb,
                                               const unsigned short* __restrict__ H2b,
                                               const float* __restrict__ es2, const float* __restrict__ ed2,
                                               const int* __restrict__ topic_ids,
                                               float* __restrict__ ppv, float* __restrict__ pl) {
    int js = blockIdx.x, h = blockIdx.y, b = blockIdx.z;
    int t = threadIdx.x;
    __shared__ float pls[64];
    __shared__ float red[256];
    int qi = topic_ids[b];
    if (t < 64) {
        int j = js * 64 + t;
        float esq = es2[((size_t)b * NH + h) * NT + qi];
        unsigned short twu = TWb[((size_t)b * NT + qi) * NT + j];
        float tw = bf2f(twu);
        float e = esq + ed2[((size_t)b * NH + h) * NT + j];
        e = fmaxf(e, 0.2f * e) * tw;
        float p = twu ? __expf(e) : 0.f;
        pls[t] = p;
        float lsum = p;
        #pragma unroll
        for (int mask = 1; mask < 64; mask <<= 1) lsum += __shfl_xor(lsum, mask);
        if (t == 0) pl[((size_t)b * NH + h) * 16 + js] = lsum;
    }
    __syncthreads();
    int o = t & 63, jg = t >> 6;
    float acc = 0.f;
    const unsigned short* hb = H2b + ((size_t)(b * NT) + js * 64 + jg * 16) * HID + h * HD + o;
    #pragma unroll
    for (int jj = 0; jj < 16; jj++)
        acc = fmaf(pls[jg * 16 + jj], bf2f(hb[(size_t)jj * HID]), acc);
    red[t] = acc; __syncthreads();
    if (t < 64) {
        float pv = red[t] + red[t + 64] + red[t + 128] + red[t + 192];
        ppv[(((size_t)b * NH + h) * 16 + js) * HD + t] = pv;
    }
}

// ---------------- final head: reduce partials -> ELU -> combined -> fc1 relu -> fc2 ----
__global__ __launch_bounds__(256) void khead(const float* __restrict__ ppv, const float* __restrict__ pl,
                                             const float* __restrict__ attr,
                                             const float* __restrict__ aW, const float* __restrict__ ab,
                                             const float* __restrict__ fc1W, const float* __restrict__ fc1b,
                                             const float* __restrict__ fc2W, const float* __restrict__ fc2b,
                                             float* __restrict__ out) {
    int b = blockIdx.x, t = threadIdx.x;
    __shared__ float comb[HID];
    __shared__ float red[256];
    __shared__ float linv[NH];
    if (t < NH) {
        float lsum = 0.f;
        #pragma unroll
        for (int js = 0; js < 16; js++) lsum += pl[((size_t)b * NH + t) * 16 + js];
        linv[t] = 1.f / lsum;
    }
    __syncthreads();
    float av = attr[b];
    for (int k = t; k < HID; k += 256) {
        int h = k >> 6, o = k & 63;
        float pv = 0.f;
        #pragma unroll
        for (int js = 0; js < 16; js++) pv += ppv[(((size_t)b * NH + h) * 16 + js) * HD + o];
        float v = pv * linv[h];
        v = v > 0.f ? v : (__expf(v) - 1.f);  // ELU
        comb[k] = v + av * aW[k] + ab[k];
    }
    __syncthreads();
    float part = 0.f;
    for (int k = t; k < HID; k += 256) {
        const float4* wr = (const float4*)(fc1W + (size_t)k * HID);
        float acc = 0.f;
        #pragma unroll 4
        for (int mm = 0; mm < HID / 4; mm++) {
            float4 w4 = wr[mm];
            float4 c4 = *(const float4*)(comb + mm * 4);
            acc += w4.x * c4.x + w4.y * c4.y + w4.z * c4.z + w4.w * c4.w;
        }
        float hk = fmaxf(acc + fc1b[k], 0.f);
        part = fmaf(hk, fc2W[k], part);
    }
    red[t] = part; __syncthreads();
    for (int s = 128; s > 0; s >>= 1) { if (t < s) red[t] += red[t + s]; __syncthreads(); }
    if (t == 0) out[b] = red[0] + fc2b[0];
}

extern "C" void kernel_launch(void* const* d_in, const int* in_sizes, int n_in,
                              void* d_out, int out_size, void* d_ws, size_t ws_size,
                              hipStream_t stream) {
    const int*   topic_ids = (const int*)d_in[0];
    const int*   adj       = (const int*)d_in[1];
    const float* tm        = (const float*)d_in[2];
    const float* attr      = (const float*)d_in[3];
    const float* emb       = (const float*)d_in[4];
    const float* sW        = (const float*)d_in[5];
    const float* sb        = (const float*)d_in[6];
    const float* aW        = (const float*)d_in[7];
    const float* ab        = (const float*)d_in[8];
    const float* gW        = (const float*)d_in[9];   // (2,8,512,64)
    const float* ga        = (const float*)d_in[10];  // (2,8,128,1)
    const float* fc1W      = (const float*)d_in[11];
    const float* fc1b      = (const float*)d_in[12];
    const float* fc2W      = (const float*)d_in[13];
    const float* fc2b      = (const float*)d_in[14];
    float* out = (float*)d_out;

    char* p = (char*)d_ws;
    unsigned short* TWb    = (unsigned short*)p; p += sizeof(short) * (size_t)NB * NT * NT;   // 16.8 MB
    unsigned short* node0b = (unsigned short*)p; p += sizeof(short) * (size_t)NT * HID;       // 1 MB
    unsigned short* Wt     = (unsigned short*)p; p += sizeof(short) * (size_t)2 * NH * HD * HID; // 1 MB
    unsigned short* Ht1    = (unsigned short*)p; p += sizeof(short) * (size_t)HID * NT;       // 1 MB
    unsigned short* node1b = (unsigned short*)p; p += sizeof(short) * (size_t)NB * NT * HID;  // 8 MB
    unsigned short* H2b    = (unsigned short*)p; p += sizeof(short) * (size_t)NB * NT * HID;  // 8 MB
    float* es1  = (float*)p; p += sizeof(float) * NH * NT;
    float* ed1  = (float*)p; p += sizeof(float) * NH * NT;
    float* es2  = (float*)p; p += sizeof(float) * NB * NH * NT;
    float* ed2  = (float*)p; p += sizeof(float) * NB * NH * NT;
    float* ppv  = (float*)p; p += sizeof(float) * NB * NH * 16 * HD;
    float* pl   = (float*)p; p += sizeof(float) * NB * NH * 16;
    float* part = (float*)p; p += sizeof(float) * 1024;

    kmax1<<<1024, 256, 0, stream>>>(tm, part);
    kcvt<<<128, 256, 0, stream>>>(gW, Wt);
    knode0<<<NT, 256, 0, stream>>>(emb, sW, sb, node0b);
    ktw<<<2048, 256, 0, stream>>>(tm, adj, part, TWb);
    // layer 1 (batch-shared): transposed bf16 Ht1 + fused es1/ed1
    kgemm_mfma<<<dim3(16, NH), 256, 0, stream>>>(node0b, Wt, ga, Ht1, nullptr, es1, ed1);
    kattn1<<<dim3(16 * NB, NH), 256, 0, stream>>>(TWb, Ht1, es1, ed1, node1b);
    // layer 2: row-major bf16 H2b + fused es2/ed2
    kgemm_mfma<<<dim3(16 * NB, NH), 256, 0, stream>>>(node1b, Wt + (size_t)NH * HD * HID,
                                                      ga + NH * 2 * HD, nullptr, H2b, es2, ed2);
    kattn2a<<<dim3(16, NH, NB), 256, 0, stream>>>(TWb, H2b, es2, ed2, topic_ids, ppv, pl);
    khead<<<NB, 256, 0, stream>>>(ppv, pl, attr, aW, ab, fc1W, fc1b, fc2W, fc2b, out);
}